// Round 5
// baseline (785.310 us; speedup 1.0000x reference)
//
#include <hip/hip_runtime.h>

#define LOG2E 1.44269504088896340736f
#define TOPK 409

typedef __attribute__((ext_vector_type(8))) short bf16x8;
typedef __attribute__((ext_vector_type(4))) float f32x4;
typedef __attribute__((ext_vector_type(4))) unsigned short us4;

__device__ __forceinline__ unsigned short f2bf(float f) {
    unsigned u = __float_as_uint(f);
    unsigned r = (u + 0x7fffu + ((u >> 16) & 1u)) >> 16;   // RNE
    return (unsigned short)r;
}
__device__ __forceinline__ float bf2f(unsigned short h) {
    return __uint_as_float(((unsigned)h) << 16);
}

// ---------------------------------------------------------------------------
// Cast X fp32 -> Xhi/Xlo bf16 (grid covers 6291456 elements exactly)
// ---------------------------------------------------------------------------
__global__ __launch_bounds__(256) void cast_x_kernel(
    const float* __restrict__ X, unsigned short* __restrict__ Xhi,
    unsigned short* __restrict__ Xlo)
{
    int i = (blockIdx.x * 256 + threadIdx.x) * 8;
    float4 a = *(const float4*)&X[i];
    float4 b = *(const float4*)&X[i + 4];
    float v[8] = {a.x, a.y, a.z, a.w, b.x, b.y, b.z, b.w};
    us4 h0, h1, l0, l1;
#pragma unroll
    for (int k = 0; k < 4; ++k) {
        unsigned short hb = f2bf(v[k]);
        h0[k] = hb; l0[k] = f2bf(v[k] - bf2f(hb));
        unsigned short hb2 = f2bf(v[4 + k]);
        h1[k] = hb2; l1[k] = f2bf(v[4 + k] - bf2f(hb2));
    }
    *(us4*)&Xhi[i] = h0; *(us4*)&Xhi[i + 4] = h1;
    *(us4*)&Xlo[i] = l0; *(us4*)&Xlo[i + 4] = l1;
}

// ---------------------------------------------------------------------------
// W[K,N] fp32 -> Th/Tl[N,K] bf16 (transpose + hi/lo split), 32x32 LDS tiles
// ---------------------------------------------------------------------------
__global__ __launch_bounds__(256) void transpose_split_kernel(
    const float* __restrict__ W, unsigned short* __restrict__ Th,
    unsigned short* __restrict__ Tl, int K, int N)
{
    __shared__ float T[32][33];
    const int tx = threadIdx.x & 31, ty = threadIdx.x >> 5;   // ty 0..7
    const int n0 = blockIdx.x * 32, k0 = blockIdx.y * 32;
#pragma unroll
    for (int r = 0; r < 4; ++r)
        T[ty + r * 8][tx] = W[(size_t)(k0 + ty + r * 8) * N + n0 + tx];
    __syncthreads();
#pragma unroll
    for (int r = 0; r < 4; ++r) {
        int nl = ty + r * 8;
        float v = T[tx][nl];
        unsigned short hb = f2bf(v);
        Th[(size_t)(n0 + nl) * K + k0 + tx] = hb;
        Tl[(size_t)(n0 + nl) * K + k0 + tx] = f2bf(v - bf2f(hb));
    }
}

// ---------------------------------------------------------------------------
// QKV GEMM via MFMA: C = X @ Wqkv + b. A = Xhi/Xlo [8192,768] bf16,
// B = Wt hi/lo [2304,768] bf16 (row n contiguous in k). 128x128 tile, BK=32.
// Q/K n-blocks: 3-pass split (hi.hi + hi.lo + lo.hi); V block: 1-pass.
// Epilogue scatters to Qhi/Qlo/Khi/Klo [H,S,64] and Vt [H,64,1024].
// ---------------------------------------------------------------------------
__global__ __launch_bounds__(256) void qkv_mfma_kernel(
    const unsigned short* __restrict__ Xhi, const unsigned short* __restrict__ Xlo,
    const unsigned short* __restrict__ Bhg, const unsigned short* __restrict__ Blg,
    const float* __restrict__ bias,
    unsigned short* __restrict__ Qhi, unsigned short* __restrict__ Qlo,
    unsigned short* __restrict__ Khi, unsigned short* __restrict__ Klo,
    unsigned short* __restrict__ Vt)
{
    __shared__ unsigned short Ah[128 * 32], Al[128 * 32];
    __shared__ unsigned short Bh[128 * 32], Bl[128 * 32];
    const int tid = threadIdx.x;
    const int n0 = blockIdx.x * 128, m0 = blockIdx.y * 128;
    const int which = n0 / 768;               // block-uniform
    const bool threep = (which < 2);
    const int lane = tid & 63, l16 = lane & 15, quad = lane >> 4;
    const int w = tid >> 6, wm = w >> 1, wn = w & 1;

    f32x4 acc[4][4];
#pragma unroll
    for (int mi = 0; mi < 4; ++mi)
#pragma unroll
        for (int ni = 0; ni < 4; ++ni) acc[mi][ni] = (f32x4){0.f, 0.f, 0.f, 0.f};

    const int r0 = tid >> 2, kc = (tid & 3) * 8;   // staging: rows r0, r0+64
    const int r1 = r0 + 64;

    for (int k0 = 0; k0 < 768; k0 += 32) {
        bf16x8 ah0 = *(const bf16x8*)&Xhi[(size_t)(m0 + r0) * 768 + k0 + kc];
        bf16x8 ah1 = *(const bf16x8*)&Xhi[(size_t)(m0 + r1) * 768 + k0 + kc];
        bf16x8 bh0 = *(const bf16x8*)&Bhg[(size_t)(n0 + r0) * 768 + k0 + kc];
        bf16x8 bh1 = *(const bf16x8*)&Bhg[(size_t)(n0 + r1) * 768 + k0 + kc];
        bf16x8 al0 = {}, al1 = {}, bl0 = {}, bl1 = {};
        if (threep) {
            al0 = *(const bf16x8*)&Xlo[(size_t)(m0 + r0) * 768 + k0 + kc];
            al1 = *(const bf16x8*)&Xlo[(size_t)(m0 + r1) * 768 + k0 + kc];
            bl0 = *(const bf16x8*)&Blg[(size_t)(n0 + r0) * 768 + k0 + kc];
            bl1 = *(const bf16x8*)&Blg[(size_t)(n0 + r1) * 768 + k0 + kc];
        }
        __syncthreads();
        *(bf16x8*)&Ah[r0 * 32 + kc] = ah0;
        *(bf16x8*)&Ah[r1 * 32 + kc] = ah1;
        *(bf16x8*)&Bh[r0 * 32 + kc] = bh0;
        *(bf16x8*)&Bh[r1 * 32 + kc] = bh1;
        if (threep) {
            *(bf16x8*)&Al[r0 * 32 + kc] = al0;
            *(bf16x8*)&Al[r1 * 32 + kc] = al1;
            *(bf16x8*)&Bl[r0 * 32 + kc] = bl0;
            *(bf16x8*)&Bl[r1 * 32 + kc] = bl1;
        }
        __syncthreads();

        bf16x8 fah[4], fal[4];
#pragma unroll
        for (int mi = 0; mi < 4; ++mi) {
            int off = (wm * 64 + mi * 16 + l16) * 32 + quad * 8;
            fah[mi] = *(const bf16x8*)&Ah[off];
            if (threep) fal[mi] = *(const bf16x8*)&Al[off];
        }
#pragma unroll
        for (int ni = 0; ni < 4; ++ni) {
            int off = (wn * 64 + ni * 16 + l16) * 32 + quad * 8;
            bf16x8 fbh = *(const bf16x8*)&Bh[off];
            if (threep) {
                bf16x8 fbl = *(const bf16x8*)&Bl[off];
#pragma unroll
                for (int mi = 0; mi < 4; ++mi) {
                    acc[mi][ni] = __builtin_amdgcn_mfma_f32_16x16x32_bf16(fah[mi], fbh, acc[mi][ni], 0, 0, 0);
                    acc[mi][ni] = __builtin_amdgcn_mfma_f32_16x16x32_bf16(fah[mi], fbl, acc[mi][ni], 0, 0, 0);
                    acc[mi][ni] = __builtin_amdgcn_mfma_f32_16x16x32_bf16(fal[mi], fbh, acc[mi][ni], 0, 0, 0);
                }
            } else {
#pragma unroll
                for (int mi = 0; mi < 4; ++mi)
                    acc[mi][ni] = __builtin_amdgcn_mfma_f32_16x16x32_bf16(fah[mi], fbh, acc[mi][ni], 0, 0, 0);
            }
        }
    }

    // Epilogue: acc[mi][ni][r] = C[m0+wm*64+mi*16+quad*4+r][n0+wn*64+ni*16+l16]
#pragma unroll
    for (int mi = 0; mi < 4; ++mi) {
#pragma unroll
        for (int ni = 0; ni < 4; ++ni) {
            int nb = n0 + wn * 64 + ni * 16 + l16;
            int rem = nb - which * 768;
            int h = rem >> 6, d = rem & 63;
            float bv = bias[nb];
#pragma unroll
            for (int r = 0; r < 4; ++r) {
                int m = m0 + wm * 64 + mi * 16 + quad * 4 + r;
                int bb = m >> 10, s = m & 1023;
                int head = bb * 12 + h;
                float val = acc[mi][ni][r] + bv;
                if (which == 2) {
                    Vt[(size_t)head * 65536 + (size_t)d * 1024 + s] = f2bf(val);
                } else {
                    unsigned short hb = f2bf(val);
                    unsigned short lb = f2bf(val - bf2f(hb));
                    size_t idx = (size_t)head * 65536 + (size_t)s * 64 + d;
                    if (which == 0) { Qhi[idx] = hb; Qlo[idx] = lb; }
                    else            { Khi[idx] = hb; Klo[idx] = lb; }
                }
            }
        }
    }
}

// ---------------------------------------------------------------------------
// Proj GEMM via MFMA (single-pass bf16): OUT = Aob @ Wproj + b, fp32 out.
// ---------------------------------------------------------------------------
__global__ __launch_bounds__(256) void proj_mfma_kernel(
    const unsigned short* __restrict__ Ag, const unsigned short* __restrict__ Bhg,
    const float* __restrict__ bias, float* __restrict__ OUT)
{
    __shared__ unsigned short Ah[128 * 32];
    __shared__ unsigned short Bh[128 * 32];
    const int tid = threadIdx.x;
    const int n0 = blockIdx.x * 128, m0 = blockIdx.y * 128;
    const int lane = tid & 63, l16 = lane & 15, quad = lane >> 4;
    const int w = tid >> 6, wm = w >> 1, wn = w & 1;

    f32x4 acc[4][4];
#pragma unroll
    for (int mi = 0; mi < 4; ++mi)
#pragma unroll
        for (int ni = 0; ni < 4; ++ni) acc[mi][ni] = (f32x4){0.f, 0.f, 0.f, 0.f};

    const int r0 = tid >> 2, kc = (tid & 3) * 8;
    const int r1 = r0 + 64;

    for (int k0 = 0; k0 < 768; k0 += 32) {
        bf16x8 ah0 = *(const bf16x8*)&Ag[(size_t)(m0 + r0) * 768 + k0 + kc];
        bf16x8 ah1 = *(const bf16x8*)&Ag[(size_t)(m0 + r1) * 768 + k0 + kc];
        bf16x8 bh0 = *(const bf16x8*)&Bhg[(size_t)(n0 + r0) * 768 + k0 + kc];
        bf16x8 bh1 = *(const bf16x8*)&Bhg[(size_t)(n0 + r1) * 768 + k0 + kc];
        __syncthreads();
        *(bf16x8*)&Ah[r0 * 32 + kc] = ah0;
        *(bf16x8*)&Ah[r1 * 32 + kc] = ah1;
        *(bf16x8*)&Bh[r0 * 32 + kc] = bh0;
        *(bf16x8*)&Bh[r1 * 32 + kc] = bh1;
        __syncthreads();

        bf16x8 fah[4];
#pragma unroll
        for (int mi = 0; mi < 4; ++mi)
            fah[mi] = *(const bf16x8*)&Ah[(wm * 64 + mi * 16 + l16) * 32 + quad * 8];
#pragma unroll
        for (int ni = 0; ni < 4; ++ni) {
            bf16x8 fbh = *(const bf16x8*)&Bh[(wn * 64 + ni * 16 + l16) * 32 + quad * 8];
#pragma unroll
            for (int mi = 0; mi < 4; ++mi)
                acc[mi][ni] = __builtin_amdgcn_mfma_f32_16x16x32_bf16(fah[mi], fbh, acc[mi][ni], 0, 0, 0);
        }
    }

#pragma unroll
    for (int mi = 0; mi < 4; ++mi)
#pragma unroll
        for (int ni = 0; ni < 4; ++ni) {
            int nb = n0 + wn * 64 + ni * 16 + l16;
            float bv = bias[nb];
#pragma unroll
            for (int r = 0; r < 4; ++r) {
                int m = m0 + wm * 64 + mi * 16 + quad * 4 + r;
                OUT[(size_t)m * 768 + nb] = acc[mi][ni][r] + bv;
            }
        }
}

// ---------------------------------------------------------------------------
// Attention. Phases 1/3 + epilogue identical to R4 (proven). Phase 2 is now
// wave-per-row: each wave handles rows 4w..4w+3 sequentially; 16 values/lane;
// exact 32-bit binary search with wave-uniform candidate counted via
// ballot + scalar popcount (no cross-lane shuffle chain in the search).
// ---------------------------------------------------------------------------
__global__ __launch_bounds__(256) void attn_kernel(
    const unsigned short* __restrict__ Qhi, const unsigned short* __restrict__ Qlo,
    const unsigned short* __restrict__ Khi, const unsigned short* __restrict__ Klo,
    const unsigned short* __restrict__ Vt, unsigned short* __restrict__ Aob)
{
    __shared__ float S[16 * 1024];   // 64 KB: scores -> P -> partials(+rsum)

    const int head = blockIdx.y;
    const int qt = blockIdx.x;       // 16-row q tile
    const int bb = head / 12, h = head - bb * 12;
    const int tid = threadIdx.x;
    const int w = tid >> 6, lane = tid & 63;
    const int l16 = lane & 15, quad = lane >> 4;
    const int r2 = w * 4 + quad;     // used by epilogue rsum store

    const size_t hbase = (size_t)head * 65536;
    const unsigned short* Qhp = Qhi + hbase + (size_t)(qt * 16) * 64;
    const unsigned short* Qlp = Qlo + hbase + (size_t)(qt * 16) * 64;
    const unsigned short* Khp = Khi + hbase;
    const unsigned short* Klp = Klo + hbase;
    const unsigned short* Vp  = Vt + hbase;   // [64][1024]

    bf16x8 qh0, qh1, ql0, ql1;
    {
        int off = l16 * 64 + quad * 8;
        qh0 = *(const bf16x8*)(Qhp + off);
        qh1 = *(const bf16x8*)(Qhp + off + 32);
        ql0 = *(const bf16x8*)(Qlp + off);
        ql1 = *(const bf16x8*)(Qlp + off + 32);
    }

    // ---- Phase 1: scores for cols [w*256, w*256+256) ----
    for (int t = 0; t < 16; ++t) {
        int col0 = w * 256 + t * 16;
        int off = (col0 + l16) * 64 + quad * 8;
        bf16x8 kh0 = *(const bf16x8*)(Khp + off);
        bf16x8 kh1 = *(const bf16x8*)(Khp + off + 32);
        bf16x8 kl0 = *(const bf16x8*)(Klp + off);
        bf16x8 kl1 = *(const bf16x8*)(Klp + off + 32);
        f32x4 acc = {0.f, 0.f, 0.f, 0.f};
        acc = __builtin_amdgcn_mfma_f32_16x16x32_bf16(qh0, kh0, acc, 0, 0, 0);
        acc = __builtin_amdgcn_mfma_f32_16x16x32_bf16(qh1, kh1, acc, 0, 0, 0);
        acc = __builtin_amdgcn_mfma_f32_16x16x32_bf16(qh0, kl0, acc, 0, 0, 0);
        acc = __builtin_amdgcn_mfma_f32_16x16x32_bf16(qh1, kl1, acc, 0, 0, 0);
        acc = __builtin_amdgcn_mfma_f32_16x16x32_bf16(ql0, kh0, acc, 0, 0, 0);
        acc = __builtin_amdgcn_mfma_f32_16x16x32_bf16(ql1, kh1, acc, 0, 0, 0);
#pragma unroll
        for (int r = 0; r < 4; ++r)
            S[(quad * 4 + r) * 1024 + col0 + l16] = acc[r] * 0.125f;
    }
    __syncthreads();

    // ---- Phase 2: wave w owns rows 4w..4w+3 sequentially; 16 values/lane ----
    float rs[4];
    for (int rr = 0; rr < 4; ++rr) {
        const int row = w * 4 + rr;
        float* Srow = &S[row << 10];
        unsigned u[16];
        float m = -1e30f;
#pragma unroll
        for (int i = 0; i < 4; ++i) {
            f32x4 v = *(const f32x4*)&Srow[(lane + (i << 6)) << 2];
#pragma unroll
            for (int k = 0; k < 4; ++k) {
                float f = v[k];
                m = fmaxf(m, f);
                unsigned uu = __float_as_uint(f);
                u[i * 4 + k] = (uu & 0x80000000u) ? ~uu : (uu | 0x80000000u);
            }
        }
#pragma unroll
        for (int off = 32; off; off >>= 1) m = fmaxf(m, __shfl_xor(m, off));

        // exact k-th largest: wave-uniform candidate, ballot + popcount
        unsigned ans = 0u;
#pragma unroll 1
        for (int bit = 31; bit >= 0; --bit) {
            unsigned cand = ans | (1u << bit);
            int cnt = 0;
#pragma unroll
            for (int i = 0; i < 16; ++i)
                cnt += (int)__popcll(__ballot(u[i] >= cand));
            if (cnt >= TOPK) ans = cand;
        }

        float ssum = 0.f;
#pragma unroll
        for (int i = 0; i < 4; ++i) {
            f32x4 e;
#pragma unroll
            for (int k = 0; k < 4; ++k) {
                unsigned uu = u[i * 4 + k];
                unsigned fb = (uu & 0x80000000u) ? (uu & 0x7fffffffu) : ~uu;
                float f = __uint_as_float(fb);
                float ev = (uu >= ans) ? exp2f((f - m) * LOG2E) : 0.f;
                ssum += ev;
                e[k] = ev;
            }
            *(f32x4*)&Srow[(lane + (i << 6)) << 2] = e;
        }
#pragma unroll
        for (int off = 32; off; off >>= 1) ssum += __shfl_xor(ssum, off);
        rs[rr] = ssum;
    }
    __syncthreads();

    // ---- Phase 3: partial O over k in [w*256, w*256+256) ----
    f32x4 oacc[4];
#pragma unroll
    for (int nt = 0; nt < 4; ++nt) oacc[nt] = (f32x4){0.f, 0.f, 0.f, 0.f};

    for (int step = 0; step < 8; ++step) {
        int k0 = w * 256 + step * 32;
        f32x4 p0 = *(const f32x4*)&S[l16 * 1024 + k0 + quad * 8];
        f32x4 p1 = *(const f32x4*)&S[l16 * 1024 + k0 + quad * 8 + 4];
        bf16x8 a;
#pragma unroll
        for (int k = 0; k < 4; ++k) a[k] = (short)f2bf(p0[k]);
#pragma unroll
        for (int k = 0; k < 4; ++k) a[4 + k] = (short)f2bf(p1[k]);
#pragma unroll
        for (int nt = 0; nt < 4; ++nt) {
            bf16x8 bfrag = *(const bf16x8*)(Vp + (size_t)(nt * 16 + l16) * 1024 + k0 + quad * 8);
            oacc[nt] = __builtin_amdgcn_mfma_f32_16x16x32_bf16(a, bfrag, oacc[nt], 0, 0, 0);
        }
    }
    __syncthreads();   // all P reads done; S reusable

    // partials: S[(w*16 + row)*64 + col], rsum at S[4096 + r]
#pragma unroll
    for (int nt = 0; nt < 4; ++nt)
#pragma unroll
        for (int r = 0; r < 4; ++r)
            S[(w * 16 + quad * 4 + r) * 64 + nt * 16 + l16] = oacc[nt][r];
    {
        float rv = (quad & 2) ? ((quad & 1) ? rs[3] : rs[2])
                              : ((quad & 1) ? rs[1] : rs[0]);
        if (l16 == 0) S[4096 + r2] = rv;
    }
    __syncthreads();

    {
        int row = tid >> 4, ds = (tid & 15) * 4;
        f32x4 o = {0.f, 0.f, 0.f, 0.f};
#pragma unroll
        for (int ww = 0; ww < 4; ++ww)
            o += *(const f32x4*)&S[(ww * 16 + row) * 64 + ds];
        float inv = 1.f / S[4096 + row];
        int srow = qt * 16 + row;
        us4 res;
#pragma unroll
        for (int k = 0; k < 4; ++k) res[k] = f2bf(o[k] * inv);
        *(us4*)&Aob[((size_t)(bb * 1024 + srow)) * 768 + h * 64 + ds] = res;
    }
}

extern "C" void kernel_launch(void* const* d_in, const int* in_sizes, int n_in,
                              void* d_out, int out_size, void* d_ws, size_t ws_size,
                              hipStream_t stream)
{
    const float* X     = (const float*)d_in[0];
    const float* Wqkv  = (const float*)d_in[1];
    const float* bqkv  = (const float*)d_in[2];
    const float* Wproj = (const float*)d_in[3];
    const float* bproj = (const float*)d_in[4];
    float* out = (float*)d_out;

    unsigned short* us = (unsigned short*)d_ws;
    const size_t P = (size_t)8192 * 768;          // 6291456
    unsigned short* Xhi = us;
    unsigned short* Xlo = Xhi + P;
    unsigned short* Wqh = Xlo + P;                // [2304][768]
    unsigned short* Wql = Wqh + (size_t)2304 * 768;
    unsigned short* Wph = Wql + (size_t)2304 * 768;  // [768][768]
    unsigned short* Wpl = Wph + (size_t)768 * 768;
    unsigned short* Qhi = Wpl + (size_t)768 * 768;
    unsigned short* Qlo = Qhi + P;
    unsigned short* Khi = Qlo + P;
    unsigned short* Klo = Khi + P;
    unsigned short* Vt  = Klo + P;
    unsigned short* Aob = Xhi;   // reuse: X consumed by qkv before attn writes Aob

    cast_x_kernel<<<3072, 256, 0, stream>>>(X, Xhi, Xlo);
    transpose_split_kernel<<<dim3(72, 24), 256, 0, stream>>>(Wqkv, Wqh, Wql, 768, 2304);
    transpose_split_kernel<<<dim3(24, 24), 256, 0, stream>>>(Wproj, Wph, Wpl, 768, 768);
    qkv_mfma_kernel<<<dim3(18, 64), 256, 0, stream>>>(Xhi, Xlo, Wqh, Wql, bqkv,
                                                      Qhi, Qlo, Khi, Klo, Vt);
    attn_kernel<<<dim3(64, 96), 256, 0, stream>>>(Qhi, Qlo, Khi, Klo, Vt, Aob);
    proj_mfma_kernel<<<dim3(6, 64), 256, 0, stream>>>(Aob, Wph, bproj, out);
}

// Round 6
// 714.663 us; speedup vs baseline: 1.0989x; 1.0989x over previous
//
#include <hip/hip_runtime.h>

#define LOG2E 1.44269504088896340736f
#define TOPK 409

typedef __attribute__((ext_vector_type(8))) short bf16x8;
typedef __attribute__((ext_vector_type(4))) float f32x4;
typedef __attribute__((ext_vector_type(4))) unsigned short us4;

__device__ __forceinline__ unsigned short f2bf(float f) {
    unsigned u = __float_as_uint(f);
    unsigned r = (u + 0x7fffu + ((u >> 16) & 1u)) >> 16;   // RNE
    return (unsigned short)r;
}
__device__ __forceinline__ float bf2f(unsigned short h) {
    return __uint_as_float(((unsigned)h) << 16);
}

// ---------------------------------------------------------------------------
// Cast X fp32 -> Xhi/Xlo bf16 (grid covers 6291456 elements exactly)
// ---------------------------------------------------------------------------
__global__ __launch_bounds__(256) void cast_x_kernel(
    const float* __restrict__ X, unsigned short* __restrict__ Xhi,
    unsigned short* __restrict__ Xlo)
{
    int i = (blockIdx.x * 256 + threadIdx.x) * 8;
    float4 a = *(const float4*)&X[i];
    float4 b = *(const float4*)&X[i + 4];
    float v[8] = {a.x, a.y, a.z, a.w, b.x, b.y, b.z, b.w};
    us4 h0, h1, l0, l1;
#pragma unroll
    for (int k = 0; k < 4; ++k) {
        unsigned short hb = f2bf(v[k]);
        h0[k] = hb; l0[k] = f2bf(v[k] - bf2f(hb));
        unsigned short hb2 = f2bf(v[4 + k]);
        h1[k] = hb2; l1[k] = f2bf(v[4 + k] - bf2f(hb2));
    }
    *(us4*)&Xhi[i] = h0; *(us4*)&Xhi[i + 4] = h1;
    *(us4*)&Xlo[i] = l0; *(us4*)&Xlo[i + 4] = l1;
}

// ---------------------------------------------------------------------------
// W[K,N] fp32 -> Th/Tl[N,K] bf16 (transpose + hi/lo split), 32x32 LDS tiles
// ---------------------------------------------------------------------------
__global__ __launch_bounds__(256) void transpose_split_kernel(
    const float* __restrict__ W, unsigned short* __restrict__ Th,
    unsigned short* __restrict__ Tl, int K, int N)
{
    __shared__ float T[32][33];
    const int tx = threadIdx.x & 31, ty = threadIdx.x >> 5;   // ty 0..7
    const int n0 = blockIdx.x * 32, k0 = blockIdx.y * 32;
#pragma unroll
    for (int r = 0; r < 4; ++r)
        T[ty + r * 8][tx] = W[(size_t)(k0 + ty + r * 8) * N + n0 + tx];
    __syncthreads();
#pragma unroll
    for (int r = 0; r < 4; ++r) {
        int nl = ty + r * 8;
        float v = T[tx][nl];
        unsigned short hb = f2bf(v);
        Th[(size_t)(n0 + nl) * K + k0 + tx] = hb;
        Tl[(size_t)(n0 + nl) * K + k0 + tx] = f2bf(v - bf2f(hb));
    }
}

// ---------------------------------------------------------------------------
// QKV GEMM via MFMA: C = X @ Wqkv + b. A = Xhi/Xlo [8192,768] bf16,
// B = Wt hi/lo [2304,768] bf16 (row n contiguous in k). 128x128 tile, BK=32.
// Q/K n-blocks: 3-pass split (hi.hi + hi.lo + lo.hi); V block: 1-pass.
// Epilogue scatters to Qhi/Qlo/Khi/Klo [H,S,64] and Vt [H,64,1024].
// ---------------------------------------------------------------------------
__global__ __launch_bounds__(256) void qkv_mfma_kernel(
    const unsigned short* __restrict__ Xhi, const unsigned short* __restrict__ Xlo,
    const unsigned short* __restrict__ Bhg, const unsigned short* __restrict__ Blg,
    const float* __restrict__ bias,
    unsigned short* __restrict__ Qhi, unsigned short* __restrict__ Qlo,
    unsigned short* __restrict__ Khi, unsigned short* __restrict__ Klo,
    unsigned short* __restrict__ Vt)
{
    __shared__ unsigned short Ah[128 * 32], Al[128 * 32];
    __shared__ unsigned short Bh[128 * 32], Bl[128 * 32];
    const int tid = threadIdx.x;
    const int n0 = blockIdx.x * 128, m0 = blockIdx.y * 128;
    const int which = n0 / 768;               // block-uniform
    const bool threep = (which < 2);
    const int lane = tid & 63, l16 = lane & 15, quad = lane >> 4;
    const int w = tid >> 6, wm = w >> 1, wn = w & 1;

    f32x4 acc[4][4];
#pragma unroll
    for (int mi = 0; mi < 4; ++mi)
#pragma unroll
        for (int ni = 0; ni < 4; ++ni) acc[mi][ni] = (f32x4){0.f, 0.f, 0.f, 0.f};

    const int r0 = tid >> 2, kc = (tid & 3) * 8;   // staging: rows r0, r0+64
    const int r1 = r0 + 64;

    for (int k0 = 0; k0 < 768; k0 += 32) {
        bf16x8 ah0 = *(const bf16x8*)&Xhi[(size_t)(m0 + r0) * 768 + k0 + kc];
        bf16x8 ah1 = *(const bf16x8*)&Xhi[(size_t)(m0 + r1) * 768 + k0 + kc];
        bf16x8 bh0 = *(const bf16x8*)&Bhg[(size_t)(n0 + r0) * 768 + k0 + kc];
        bf16x8 bh1 = *(const bf16x8*)&Bhg[(size_t)(n0 + r1) * 768 + k0 + kc];
        bf16x8 al0 = {}, al1 = {}, bl0 = {}, bl1 = {};
        if (threep) {
            al0 = *(const bf16x8*)&Xlo[(size_t)(m0 + r0) * 768 + k0 + kc];
            al1 = *(const bf16x8*)&Xlo[(size_t)(m0 + r1) * 768 + k0 + kc];
            bl0 = *(const bf16x8*)&Blg[(size_t)(n0 + r0) * 768 + k0 + kc];
            bl1 = *(const bf16x8*)&Blg[(size_t)(n0 + r1) * 768 + k0 + kc];
        }
        __syncthreads();
        *(bf16x8*)&Ah[r0 * 32 + kc] = ah0;
        *(bf16x8*)&Ah[r1 * 32 + kc] = ah1;
        *(bf16x8*)&Bh[r0 * 32 + kc] = bh0;
        *(bf16x8*)&Bh[r1 * 32 + kc] = bh1;
        if (threep) {
            *(bf16x8*)&Al[r0 * 32 + kc] = al0;
            *(bf16x8*)&Al[r1 * 32 + kc] = al1;
            *(bf16x8*)&Bl[r0 * 32 + kc] = bl0;
            *(bf16x8*)&Bl[r1 * 32 + kc] = bl1;
        }
        __syncthreads();

        bf16x8 fah[4], fal[4];
#pragma unroll
        for (int mi = 0; mi < 4; ++mi) {
            int off = (wm * 64 + mi * 16 + l16) * 32 + quad * 8;
            fah[mi] = *(const bf16x8*)&Ah[off];
            if (threep) fal[mi] = *(const bf16x8*)&Al[off];
        }
#pragma unroll
        for (int ni = 0; ni < 4; ++ni) {
            int off = (wn * 64 + ni * 16 + l16) * 32 + quad * 8;
            bf16x8 fbh = *(const bf16x8*)&Bh[off];
            if (threep) {
                bf16x8 fbl = *(const bf16x8*)&Bl[off];
#pragma unroll
                for (int mi = 0; mi < 4; ++mi) {
                    acc[mi][ni] = __builtin_amdgcn_mfma_f32_16x16x32_bf16(fah[mi], fbh, acc[mi][ni], 0, 0, 0);
                    acc[mi][ni] = __builtin_amdgcn_mfma_f32_16x16x32_bf16(fah[mi], fbl, acc[mi][ni], 0, 0, 0);
                    acc[mi][ni] = __builtin_amdgcn_mfma_f32_16x16x32_bf16(fal[mi], fbh, acc[mi][ni], 0, 0, 0);
                }
            } else {
#pragma unroll
                for (int mi = 0; mi < 4; ++mi)
                    acc[mi][ni] = __builtin_amdgcn_mfma_f32_16x16x32_bf16(fah[mi], fbh, acc[mi][ni], 0, 0, 0);
            }
        }
    }

    // Epilogue: acc[mi][ni][r] = C[m0+wm*64+mi*16+quad*4+r][n0+wn*64+ni*16+l16]
#pragma unroll
    for (int mi = 0; mi < 4; ++mi) {
#pragma unroll
        for (int ni = 0; ni < 4; ++ni) {
            int nb = n0 + wn * 64 + ni * 16 + l16;
            int rem = nb - which * 768;
            int h = rem >> 6, d = rem & 63;
            float bv = bias[nb];
#pragma unroll
            for (int r = 0; r < 4; ++r) {
                int m = m0 + wm * 64 + mi * 16 + quad * 4 + r;
                int bb = m >> 10, s = m & 1023;
                int head = bb * 12 + h;
                float val = acc[mi][ni][r] + bv;
                if (which == 2) {
                    Vt[(size_t)head * 65536 + (size_t)d * 1024 + s] = f2bf(val);
                } else {
                    unsigned short hb = f2bf(val);
                    unsigned short lb = f2bf(val - bf2f(hb));
                    size_t idx = (size_t)head * 65536 + (size_t)s * 64 + d;
                    if (which == 0) { Qhi[idx] = hb; Qlo[idx] = lb; }
                    else            { Khi[idx] = hb; Klo[idx] = lb; }
                }
            }
        }
    }
}

// ---------------------------------------------------------------------------
// Proj GEMM via MFMA (single-pass bf16): OUT = Aob @ Wproj + b, fp32 out.
// ---------------------------------------------------------------------------
__global__ __launch_bounds__(256) void proj_mfma_kernel(
    const unsigned short* __restrict__ Ag, const unsigned short* __restrict__ Bhg,
    const float* __restrict__ bias, float* __restrict__ OUT)
{
    __shared__ unsigned short Ah[128 * 32];
    __shared__ unsigned short Bh[128 * 32];
    const int tid = threadIdx.x;
    const int n0 = blockIdx.x * 128, m0 = blockIdx.y * 128;
    const int lane = tid & 63, l16 = lane & 15, quad = lane >> 4;
    const int w = tid >> 6, wm = w >> 1, wn = w & 1;

    f32x4 acc[4][4];
#pragma unroll
    for (int mi = 0; mi < 4; ++mi)
#pragma unroll
        for (int ni = 0; ni < 4; ++ni) acc[mi][ni] = (f32x4){0.f, 0.f, 0.f, 0.f};

    const int r0 = tid >> 2, kc = (tid & 3) * 8;
    const int r1 = r0 + 64;

    for (int k0 = 0; k0 < 768; k0 += 32) {
        bf16x8 ah0 = *(const bf16x8*)&Ag[(size_t)(m0 + r0) * 768 + k0 + kc];
        bf16x8 ah1 = *(const bf16x8*)&Ag[(size_t)(m0 + r1) * 768 + k0 + kc];
        bf16x8 bh0 = *(const bf16x8*)&Bhg[(size_t)(n0 + r0) * 768 + k0 + kc];
        bf16x8 bh1 = *(const bf16x8*)&Bhg[(size_t)(n0 + r1) * 768 + k0 + kc];
        __syncthreads();
        *(bf16x8*)&Ah[r0 * 32 + kc] = ah0;
        *(bf16x8*)&Ah[r1 * 32 + kc] = ah1;
        *(bf16x8*)&Bh[r0 * 32 + kc] = bh0;
        *(bf16x8*)&Bh[r1 * 32 + kc] = bh1;
        __syncthreads();

        bf16x8 fah[4];
#pragma unroll
        for (int mi = 0; mi < 4; ++mi)
            fah[mi] = *(const bf16x8*)&Ah[(wm * 64 + mi * 16 + l16) * 32 + quad * 8];
#pragma unroll
        for (int ni = 0; ni < 4; ++ni) {
            bf16x8 fbh = *(const bf16x8*)&Bh[(wn * 64 + ni * 16 + l16) * 32 + quad * 8];
#pragma unroll
            for (int mi = 0; mi < 4; ++mi)
                acc[mi][ni] = __builtin_amdgcn_mfma_f32_16x16x32_bf16(fah[mi], fbh, acc[mi][ni], 0, 0, 0);
        }
    }

#pragma unroll
    for (int mi = 0; mi < 4; ++mi)
#pragma unroll
        for (int ni = 0; ni < 4; ++ni) {
            int nb = n0 + wn * 64 + ni * 16 + l16;
            float bv = bias[nb];
#pragma unroll
            for (int r = 0; r < 4; ++r) {
                int m = m0 + wm * 64 + mi * 16 + quad * 4 + r;
                OUT[(size_t)m * 768 + nb] = acc[mi][ni][r] + bv;
            }
        }
}

// ---------------------------------------------------------------------------
// Attention. Phases 1/3 + epilogue identical to R4/R5 (proven). Phase 2:
// wave w owns rows 4w..4w+3 with all 4 binary searches INTERLEAVED in one
// bit-loop (4 independent dep chains -> issue-bound, not latency-bound),
// plus exact early exit: when count(>=cand)==TOPK the candidate already
// separates exactly the top-409 set, so the row retires (~12-16 bits typical
// instead of 32). All loop conditions / ans updates are scalar-uniform.
// ---------------------------------------------------------------------------
__global__ __launch_bounds__(256) void attn_kernel(
    const unsigned short* __restrict__ Qhi, const unsigned short* __restrict__ Qlo,
    const unsigned short* __restrict__ Khi, const unsigned short* __restrict__ Klo,
    const unsigned short* __restrict__ Vt, unsigned short* __restrict__ Aob)
{
    __shared__ float S[16 * 1024];   // 64 KB: scores -> P -> partials(+rsum)

    const int head = blockIdx.y;
    const int qt = blockIdx.x;       // 16-row q tile
    const int bb = head / 12, h = head - bb * 12;
    const int tid = threadIdx.x;
    const int w = tid >> 6, lane = tid & 63;
    const int l16 = lane & 15, quad = lane >> 4;
    const int r2 = w * 4 + quad;     // used by epilogue rsum store

    const size_t hbase = (size_t)head * 65536;
    const unsigned short* Qhp = Qhi + hbase + (size_t)(qt * 16) * 64;
    const unsigned short* Qlp = Qlo + hbase + (size_t)(qt * 16) * 64;
    const unsigned short* Khp = Khi + hbase;
    const unsigned short* Klp = Klo + hbase;
    const unsigned short* Vp  = Vt + hbase;   // [64][1024]

    bf16x8 qh0, qh1, ql0, ql1;
    {
        int off = l16 * 64 + quad * 8;
        qh0 = *(const bf16x8*)(Qhp + off);
        qh1 = *(const bf16x8*)(Qhp + off + 32);
        ql0 = *(const bf16x8*)(Qlp + off);
        ql1 = *(const bf16x8*)(Qlp + off + 32);
    }

    // ---- Phase 1: scores for cols [w*256, w*256+256) ----
    for (int t = 0; t < 16; ++t) {
        int col0 = w * 256 + t * 16;
        int off = (col0 + l16) * 64 + quad * 8;
        bf16x8 kh0 = *(const bf16x8*)(Khp + off);
        bf16x8 kh1 = *(const bf16x8*)(Khp + off + 32);
        bf16x8 kl0 = *(const bf16x8*)(Klp + off);
        bf16x8 kl1 = *(const bf16x8*)(Klp + off + 32);
        f32x4 acc = {0.f, 0.f, 0.f, 0.f};
        acc = __builtin_amdgcn_mfma_f32_16x16x32_bf16(qh0, kh0, acc, 0, 0, 0);
        acc = __builtin_amdgcn_mfma_f32_16x16x32_bf16(qh1, kh1, acc, 0, 0, 0);
        acc = __builtin_amdgcn_mfma_f32_16x16x32_bf16(qh0, kl0, acc, 0, 0, 0);
        acc = __builtin_amdgcn_mfma_f32_16x16x32_bf16(qh1, kl1, acc, 0, 0, 0);
        acc = __builtin_amdgcn_mfma_f32_16x16x32_bf16(ql0, kh0, acc, 0, 0, 0);
        acc = __builtin_amdgcn_mfma_f32_16x16x32_bf16(ql1, kh1, acc, 0, 0, 0);
#pragma unroll
        for (int r = 0; r < 4; ++r)
            S[(quad * 4 + r) * 1024 + col0 + l16] = acc[r] * 0.125f;
    }
    __syncthreads();

    // ---- Phase 2: rows 4w..4w+3 interleaved; 16 values/lane/row ----
    float rs[4];
    {
        unsigned u[4][16];
        float m[4];
#pragma unroll
        for (int rr = 0; rr < 4; ++rr) {
            const float* Srow = &S[(w * 4 + rr) << 10];
            float mloc = -1e30f;
#pragma unroll
            for (int i = 0; i < 4; ++i) {
                f32x4 v = *(const f32x4*)&Srow[(lane + (i << 6)) << 2];
#pragma unroll
                for (int k = 0; k < 4; ++k) {
                    float f = v[k];
                    mloc = fmaxf(mloc, f);
                    unsigned uu = __float_as_uint(f);
                    u[rr][i * 4 + k] = (uu & 0x80000000u) ? ~uu : (uu | 0x80000000u);
                }
            }
            m[rr] = mloc;
        }
#pragma unroll
        for (int off = 32; off; off >>= 1)
#pragma unroll
            for (int rr = 0; rr < 4; ++rr)
                m[rr] = fmaxf(m[rr], __shfl_xor(m[rr], off));

        unsigned ans[4] = {0u, 0u, 0u, 0u};
        int done = 0;
#pragma unroll 1
        for (int bit = 31; bit >= 0; --bit) {
            if (done == 15) break;
#pragma unroll
            for (int rr = 0; rr < 4; ++rr) {
                unsigned cand = ans[rr] | (1u << bit);
                int cnt = 0;
#pragma unroll
                for (int i = 0; i < 16; ++i)
                    cnt += (int)__popcll(__ballot(u[rr][i] >= cand));
                if (!((done >> rr) & 1) && cnt >= TOPK) {
                    ans[rr] = cand;
                    if (cnt == TOPK) done |= (1 << rr);
                }
            }
        }

        // masked exp (base = row max), store in place, row sums interleaved
#pragma unroll
        for (int rr = 0; rr < 4; ++rr) {
            float* Srow = &S[(w * 4 + rr) << 10];
            float ssum = 0.f;
#pragma unroll
            for (int i = 0; i < 4; ++i) {
                f32x4 e;
#pragma unroll
                for (int k = 0; k < 4; ++k) {
                    unsigned uu = u[rr][i * 4 + k];
                    unsigned fb = (uu & 0x80000000u) ? (uu & 0x7fffffffu) : ~uu;
                    float f = __uint_as_float(fb);
                    float ev = (uu >= ans[rr]) ? exp2f((f - m[rr]) * LOG2E) : 0.f;
                    ssum += ev;
                    e[k] = ev;
                }
                *(f32x4*)&Srow[(lane + (i << 6)) << 2] = e;
            }
            rs[rr] = ssum;
        }
#pragma unroll
        for (int off = 32; off; off >>= 1)
#pragma unroll
            for (int rr = 0; rr < 4; ++rr)
                rs[rr] += __shfl_xor(rs[rr], off);
    }
    __syncthreads();

    // ---- Phase 3: partial O over k in [w*256, w*256+256) ----
    f32x4 oacc[4];
#pragma unroll
    for (int nt = 0; nt < 4; ++nt) oacc[nt] = (f32x4){0.f, 0.f, 0.f, 0.f};

    for (int step = 0; step < 8; ++step) {
        int k0 = w * 256 + step * 32;
        f32x4 p0 = *(const f32x4*)&S[l16 * 1024 + k0 + quad * 8];
        f32x4 p1 = *(const f32x4*)&S[l16 * 1024 + k0 + quad * 8 + 4];
        bf16x8 a;
#pragma unroll
        for (int k = 0; k < 4; ++k) a[k] = (short)f2bf(p0[k]);
#pragma unroll
        for (int k = 0; k < 4; ++k) a[4 + k] = (short)f2bf(p1[k]);
#pragma unroll
        for (int nt = 0; nt < 4; ++nt) {
            bf16x8 bfrag = *(const bf16x8*)(Vp + (size_t)(nt * 16 + l16) * 1024 + k0 + quad * 8);
            oacc[nt] = __builtin_amdgcn_mfma_f32_16x16x32_bf16(a, bfrag, oacc[nt], 0, 0, 0);
        }
    }
    __syncthreads();   // all P reads done; S reusable

    // partials: S[(w*16 + row)*64 + col], rsum at S[4096 + r]
#pragma unroll
    for (int nt = 0; nt < 4; ++nt)
#pragma unroll
        for (int r = 0; r < 4; ++r)
            S[(w * 16 + quad * 4 + r) * 64 + nt * 16 + l16] = oacc[nt][r];
    {
        float rv = (quad & 2) ? ((quad & 1) ? rs[3] : rs[2])
                              : ((quad & 1) ? rs[1] : rs[0]);
        if (l16 == 0) S[4096 + r2] = rv;
    }
    __syncthreads();

    {
        int row = tid >> 4, ds = (tid & 15) * 4;
        f32x4 o = {0.f, 0.f, 0.f, 0.f};
#pragma unroll
        for (int ww = 0; ww < 4; ++ww)
            o += *(const f32x4*)&S[(ww * 16 + row) * 64 + ds];
        float inv = 1.f / S[4096 + row];
        int srow = qt * 16 + row;
        us4 res;
#pragma unroll
        for (int k = 0; k < 4; ++k) res[k] = f2bf(o[k] * inv);
        *(us4*)&Aob[((size_t)(bb * 1024 + srow)) * 768 + h * 64 + ds] = res;
    }
}

extern "C" void kernel_launch(void* const* d_in, const int* in_sizes, int n_in,
                              void* d_out, int out_size, void* d_ws, size_t ws_size,
                              hipStream_t stream)
{
    const float* X     = (const float*)d_in[0];
    const float* Wqkv  = (const float*)d_in[1];
    const float* bqkv  = (const float*)d_in[2];
    const float* Wproj = (const float*)d_in[3];
    const float* bproj = (const float*)d_in[4];
    float* out = (float*)d_out;

    unsigned short* us = (unsigned short*)d_ws;
    const size_t P = (size_t)8192 * 768;          // 6291456
    unsigned short* Xhi = us;
    unsigned short* Xlo = Xhi + P;
    unsigned short* Wqh = Xlo + P;                // [2304][768]
    unsigned short* Wql = Wqh + (size_t)2304 * 768;
    unsigned short* Wph = Wql + (size_t)2304 * 768;  // [768][768]
    unsigned short* Wpl = Wph + (size_t)768 * 768;
    unsigned short* Qhi = Wpl + (size_t)768 * 768;
    unsigned short* Qlo = Qhi + P;
    unsigned short* Khi = Qlo + P;
    unsigned short* Klo = Khi + P;
    unsigned short* Vt  = Klo + P;
    unsigned short* Aob = Xhi;   // reuse: X consumed by qkv before attn writes Aob

    cast_x_kernel<<<3072, 256, 0, stream>>>(X, Xhi, Xlo);
    transpose_split_kernel<<<dim3(72, 24), 256, 0, stream>>>(Wqkv, Wqh, Wql, 768, 2304);
    transpose_split_kernel<<<dim3(24, 24), 256, 0, stream>>>(Wproj, Wph, Wpl, 768, 768);
    qkv_mfma_kernel<<<dim3(18, 64), 256, 0, stream>>>(Xhi, Xlo, Wqh, Wql, bqkv,
                                                      Qhi, Qlo, Khi, Klo, Vt);
    attn_kernel<<<dim3(64, 96), 256, 0, stream>>>(Qhi, Qlo, Khi, Klo, Vt, Aob);
    proj_mfma_kernel<<<dim3(6, 64), 256, 0, stream>>>(Aob, Wph, bproj, out);
}

// Round 7
// 613.887 us; speedup vs baseline: 1.2792x; 1.1642x over previous
//
#include <hip/hip_runtime.h>

#define LOG2E 1.44269504088896340736f
#define TOPK 409

typedef __attribute__((ext_vector_type(8))) short bf16x8;
typedef __attribute__((ext_vector_type(4))) float f32x4;
typedef __attribute__((ext_vector_type(4))) unsigned short us4;

__device__ __forceinline__ unsigned short f2bf(float f) {
    unsigned u = __float_as_uint(f);
    unsigned r = (u + 0x7fffu + ((u >> 16) & 1u)) >> 16;   // RNE
    return (unsigned short)r;
}
__device__ __forceinline__ float bf2f(unsigned short h) {
    return __uint_as_float(((unsigned)h) << 16);
}

// ---------------------------------------------------------------------------
// Cast X fp32 -> Xhi/Xlo bf16 (grid covers 6291456 elements exactly)
// ---------------------------------------------------------------------------
__global__ __launch_bounds__(256) void cast_x_kernel(
    const float* __restrict__ X, unsigned short* __restrict__ Xhi,
    unsigned short* __restrict__ Xlo)
{
    int i = (blockIdx.x * 256 + threadIdx.x) * 8;
    float4 a = *(const float4*)&X[i];
    float4 b = *(const float4*)&X[i + 4];
    float v[8] = {a.x, a.y, a.z, a.w, b.x, b.y, b.z, b.w};
    us4 h0, h1, l0, l1;
#pragma unroll
    for (int k = 0; k < 4; ++k) {
        unsigned short hb = f2bf(v[k]);
        h0[k] = hb; l0[k] = f2bf(v[k] - bf2f(hb));
        unsigned short hb2 = f2bf(v[4 + k]);
        h1[k] = hb2; l1[k] = f2bf(v[4 + k] - bf2f(hb2));
    }
    *(us4*)&Xhi[i] = h0; *(us4*)&Xhi[i + 4] = h1;
    *(us4*)&Xlo[i] = l0; *(us4*)&Xlo[i + 4] = l1;
}

// ---------------------------------------------------------------------------
// W[K,N] fp32 -> Th/Tl[N,K] bf16 (transpose + hi/lo split), 32x32 LDS tiles
// ---------------------------------------------------------------------------
__global__ __launch_bounds__(256) void transpose_split_kernel(
    const float* __restrict__ W, unsigned short* __restrict__ Th,
    unsigned short* __restrict__ Tl, int K, int N)
{
    __shared__ float T[32][33];
    const int tx = threadIdx.x & 31, ty = threadIdx.x >> 5;   // ty 0..7
    const int n0 = blockIdx.x * 32, k0 = blockIdx.y * 32;
#pragma unroll
    for (int r = 0; r < 4; ++r)
        T[ty + r * 8][tx] = W[(size_t)(k0 + ty + r * 8) * N + n0 + tx];
    __syncthreads();
#pragma unroll
    for (int r = 0; r < 4; ++r) {
        int nl = ty + r * 8;
        float v = T[tx][nl];
        unsigned short hb = f2bf(v);
        Th[(size_t)(n0 + nl) * K + k0 + tx] = hb;
        Tl[(size_t)(n0 + nl) * K + k0 + tx] = f2bf(v - bf2f(hb));
    }
}

// ---------------------------------------------------------------------------
// QKV GEMM via MFMA (unchanged from R4/R6 — proven)
// ---------------------------------------------------------------------------
__global__ __launch_bounds__(256) void qkv_mfma_kernel(
    const unsigned short* __restrict__ Xhi, const unsigned short* __restrict__ Xlo,
    const unsigned short* __restrict__ Bhg, const unsigned short* __restrict__ Blg,
    const float* __restrict__ bias,
    unsigned short* __restrict__ Qhi, unsigned short* __restrict__ Qlo,
    unsigned short* __restrict__ Khi, unsigned short* __restrict__ Klo,
    unsigned short* __restrict__ Vt)
{
    __shared__ unsigned short Ah[128 * 32], Al[128 * 32];
    __shared__ unsigned short Bh[128 * 32], Bl[128 * 32];
    const int tid = threadIdx.x;
    const int n0 = blockIdx.x * 128, m0 = blockIdx.y * 128;
    const int which = n0 / 768;               // block-uniform
    const bool threep = (which < 2);
    const int lane = tid & 63, l16 = lane & 15, quad = lane >> 4;
    const int w = tid >> 6, wm = w >> 1, wn = w & 1;

    f32x4 acc[4][4];
#pragma unroll
    for (int mi = 0; mi < 4; ++mi)
#pragma unroll
        for (int ni = 0; ni < 4; ++ni) acc[mi][ni] = (f32x4){0.f, 0.f, 0.f, 0.f};

    const int r0 = tid >> 2, kc = (tid & 3) * 8;   // staging: rows r0, r0+64
    const int r1 = r0 + 64;

    for (int k0 = 0; k0 < 768; k0 += 32) {
        bf16x8 ah0 = *(const bf16x8*)&Xhi[(size_t)(m0 + r0) * 768 + k0 + kc];
        bf16x8 ah1 = *(const bf16x8*)&Xhi[(size_t)(m0 + r1) * 768 + k0 + kc];
        bf16x8 bh0 = *(const bf16x8*)&Bhg[(size_t)(n0 + r0) * 768 + k0 + kc];
        bf16x8 bh1 = *(const bf16x8*)&Bhg[(size_t)(n0 + r1) * 768 + k0 + kc];
        bf16x8 al0 = {}, al1 = {}, bl0 = {}, bl1 = {};
        if (threep) {
            al0 = *(const bf16x8*)&Xlo[(size_t)(m0 + r0) * 768 + k0 + kc];
            al1 = *(const bf16x8*)&Xlo[(size_t)(m0 + r1) * 768 + k0 + kc];
            bl0 = *(const bf16x8*)&Blg[(size_t)(n0 + r0) * 768 + k0 + kc];
            bl1 = *(const bf16x8*)&Blg[(size_t)(n0 + r1) * 768 + k0 + kc];
        }
        __syncthreads();
        *(bf16x8*)&Ah[r0 * 32 + kc] = ah0;
        *(bf16x8*)&Ah[r1 * 32 + kc] = ah1;
        *(bf16x8*)&Bh[r0 * 32 + kc] = bh0;
        *(bf16x8*)&Bh[r1 * 32 + kc] = bh1;
        if (threep) {
            *(bf16x8*)&Al[r0 * 32 + kc] = al0;
            *(bf16x8*)&Al[r1 * 32 + kc] = al1;
            *(bf16x8*)&Bl[r0 * 32 + kc] = bl0;
            *(bf16x8*)&Bl[r1 * 32 + kc] = bl1;
        }
        __syncthreads();

        bf16x8 fah[4], fal[4];
#pragma unroll
        for (int mi = 0; mi < 4; ++mi) {
            int off = (wm * 64 + mi * 16 + l16) * 32 + quad * 8;
            fah[mi] = *(const bf16x8*)&Ah[off];
            if (threep) fal[mi] = *(const bf16x8*)&Al[off];
        }
#pragma unroll
        for (int ni = 0; ni < 4; ++ni) {
            int off = (wn * 64 + ni * 16 + l16) * 32 + quad * 8;
            bf16x8 fbh = *(const bf16x8*)&Bh[off];
            if (threep) {
                bf16x8 fbl = *(const bf16x8*)&Bl[off];
#pragma unroll
                for (int mi = 0; mi < 4; ++mi) {
                    acc[mi][ni] = __builtin_amdgcn_mfma_f32_16x16x32_bf16(fah[mi], fbh, acc[mi][ni], 0, 0, 0);
                    acc[mi][ni] = __builtin_amdgcn_mfma_f32_16x16x32_bf16(fah[mi], fbl, acc[mi][ni], 0, 0, 0);
                    acc[mi][ni] = __builtin_amdgcn_mfma_f32_16x16x32_bf16(fal[mi], fbh, acc[mi][ni], 0, 0, 0);
                }
            } else {
#pragma unroll
                for (int mi = 0; mi < 4; ++mi)
                    acc[mi][ni] = __builtin_amdgcn_mfma_f32_16x16x32_bf16(fah[mi], fbh, acc[mi][ni], 0, 0, 0);
            }
        }
    }

#pragma unroll
    for (int mi = 0; mi < 4; ++mi) {
#pragma unroll
        for (int ni = 0; ni < 4; ++ni) {
            int nb = n0 + wn * 64 + ni * 16 + l16;
            int rem = nb - which * 768;
            int h = rem >> 6, d = rem & 63;
            float bv = bias[nb];
#pragma unroll
            for (int r = 0; r < 4; ++r) {
                int m = m0 + wm * 64 + mi * 16 + quad * 4 + r;
                int bb = m >> 10, s = m & 1023;
                int head = bb * 12 + h;
                float val = acc[mi][ni][r] + bv;
                if (which == 2) {
                    Vt[(size_t)head * 65536 + (size_t)d * 1024 + s] = f2bf(val);
                } else {
                    unsigned short hb = f2bf(val);
                    unsigned short lb = f2bf(val - bf2f(hb));
                    size_t idx = (size_t)head * 65536 + (size_t)s * 64 + d;
                    if (which == 0) { Qhi[idx] = hb; Qlo[idx] = lb; }
                    else            { Khi[idx] = hb; Klo[idx] = lb; }
                }
            }
        }
    }
}

// ---------------------------------------------------------------------------
// Proj GEMM via MFMA (unchanged from R4/R6 — proven)
// ---------------------------------------------------------------------------
__global__ __launch_bounds__(256) void proj_mfma_kernel(
    const unsigned short* __restrict__ Ag, const unsigned short* __restrict__ Bhg,
    const float* __restrict__ bias, float* __restrict__ OUT)
{
    __shared__ unsigned short Ah[128 * 32];
    __shared__ unsigned short Bh[128 * 32];
    const int tid = threadIdx.x;
    const int n0 = blockIdx.x * 128, m0 = blockIdx.y * 128;
    const int lane = tid & 63, l16 = lane & 15, quad = lane >> 4;
    const int w = tid >> 6, wm = w >> 1, wn = w & 1;

    f32x4 acc[4][4];
#pragma unroll
    for (int mi = 0; mi < 4; ++mi)
#pragma unroll
        for (int ni = 0; ni < 4; ++ni) acc[mi][ni] = (f32x4){0.f, 0.f, 0.f, 0.f};

    const int r0 = tid >> 2, kc = (tid & 3) * 8;
    const int r1 = r0 + 64;

    for (int k0 = 0; k0 < 768; k0 += 32) {
        bf16x8 ah0 = *(const bf16x8*)&Ag[(size_t)(m0 + r0) * 768 + k0 + kc];
        bf16x8 ah1 = *(const bf16x8*)&Ag[(size_t)(m0 + r1) * 768 + k0 + kc];
        bf16x8 bh0 = *(const bf16x8*)&Bhg[(size_t)(n0 + r0) * 768 + k0 + kc];
        bf16x8 bh1 = *(const bf16x8*)&Bhg[(size_t)(n0 + r1) * 768 + k0 + kc];
        __syncthreads();
        *(bf16x8*)&Ah[r0 * 32 + kc] = ah0;
        *(bf16x8*)&Ah[r1 * 32 + kc] = ah1;
        *(bf16x8*)&Bh[r0 * 32 + kc] = bh0;
        *(bf16x8*)&Bh[r1 * 32 + kc] = bh1;
        __syncthreads();

        bf16x8 fah[4];
#pragma unroll
        for (int mi = 0; mi < 4; ++mi)
            fah[mi] = *(const bf16x8*)&Ah[(wm * 64 + mi * 16 + l16) * 32 + quad * 8];
#pragma unroll
        for (int ni = 0; ni < 4; ++ni) {
            bf16x8 fbh = *(const bf16x8*)&Bh[(wn * 64 + ni * 16 + l16) * 32 + quad * 8];
#pragma unroll
            for (int mi = 0; mi < 4; ++mi)
                acc[mi][ni] = __builtin_amdgcn_mfma_f32_16x16x32_bf16(fah[mi], fbh, acc[mi][ni], 0, 0, 0);
        }
    }

#pragma unroll
    for (int mi = 0; mi < 4; ++mi)
#pragma unroll
        for (int ni = 0; ni < 4; ++ni) {
            int nb = n0 + wn * 64 + ni * 16 + l16;
            float bv = bias[nb];
#pragma unroll
            for (int r = 0; r < 4; ++r) {
                int m = m0 + wm * 64 + mi * 16 + quad * 4 + r;
                OUT[(size_t)m * 768 + nb] = acc[mi][ni][r] + bv;
            }
        }
}

// ---------------------------------------------------------------------------
// Attention, 512 threads (8 waves), 16 q-rows/block, 64 KB LDS.
//  Phase 1: wave w computes score cols [w*128,(w+1)*128) via MFMA -> S fp32.
//  Phase 2: wave w owns rows {2w,2w+1}: load row values to registers,
//           __syncthreads, interleaved exact binary search (ballot+popcount,
//           early exit on cnt==TOPK), masked exp -> write P as bf16 into
//           Pb (aliases S; safe after the barrier). Row stride 1032 shorts
//           -> phase-3 fragment reads are 2-way conflict (free).
//  Phase 3: O-partial over k-strip [w*128,(w+1)*128) via bf16 MFMA, P frags
//           are single ds_read_b128 from Pb; cross-wave reduce via LDS.
// ---------------------------------------------------------------------------
__global__ __launch_bounds__(512, 4) void attn_kernel(
    const unsigned short* __restrict__ Qhi, const unsigned short* __restrict__ Qlo,
    const unsigned short* __restrict__ Khi, const unsigned short* __restrict__ Klo,
    const unsigned short* __restrict__ Vt, unsigned short* __restrict__ Aob)
{
    __shared__ float S[16 * 1024];   // 64 KB. Later: Pb bf16 (33 KB) + partials
    unsigned short* Pb = (unsigned short*)S;   // [16][1032] shorts

    const int head = blockIdx.y;
    const int qt = blockIdx.x;       // 16-row q tile
    const int bb = head / 12, h = head - bb * 12;
    const int tid = threadIdx.x;
    const int w = tid >> 6, lane = tid & 63;
    const int l16 = lane & 15, quad = lane >> 4;

    const size_t hbase = (size_t)head * 65536;
    const unsigned short* Qhp = Qhi + hbase + (size_t)(qt * 16) * 64;
    const unsigned short* Qlp = Qlo + hbase + (size_t)(qt * 16) * 64;
    const unsigned short* Khp = Khi + hbase;
    const unsigned short* Klp = Klo + hbase;
    const unsigned short* Vp  = Vt + hbase;   // [64][1024]

    bf16x8 qh0, qh1, ql0, ql1;
    {
        int off = l16 * 64 + quad * 8;
        qh0 = *(const bf16x8*)(Qhp + off);
        qh1 = *(const bf16x8*)(Qhp + off + 32);
        ql0 = *(const bf16x8*)(Qlp + off);
        ql1 = *(const bf16x8*)(Qlp + off + 32);
    }

    // ---- Phase 1: scores for cols [w*128, w*128+128) ----
    for (int t = 0; t < 8; ++t) {
        int col0 = w * 128 + t * 16;
        int off = (col0 + l16) * 64 + quad * 8;
        bf16x8 kh0 = *(const bf16x8*)(Khp + off);
        bf16x8 kh1 = *(const bf16x8*)(Khp + off + 32);
        bf16x8 kl0 = *(const bf16x8*)(Klp + off);
        bf16x8 kl1 = *(const bf16x8*)(Klp + off + 32);
        f32x4 acc = {0.f, 0.f, 0.f, 0.f};
        acc = __builtin_amdgcn_mfma_f32_16x16x32_bf16(qh0, kh0, acc, 0, 0, 0);
        acc = __builtin_amdgcn_mfma_f32_16x16x32_bf16(qh1, kh1, acc, 0, 0, 0);
        acc = __builtin_amdgcn_mfma_f32_16x16x32_bf16(qh0, kl0, acc, 0, 0, 0);
        acc = __builtin_amdgcn_mfma_f32_16x16x32_bf16(qh1, kl1, acc, 0, 0, 0);
        acc = __builtin_amdgcn_mfma_f32_16x16x32_bf16(ql0, kh0, acc, 0, 0, 0);
        acc = __builtin_amdgcn_mfma_f32_16x16x32_bf16(ql1, kh1, acc, 0, 0, 0);
#pragma unroll
        for (int r = 0; r < 4; ++r)
            S[(quad * 4 + r) * 1024 + col0 + l16] = acc[r] * 0.125f;
    }
    __syncthreads();

    // ---- Phase 2: wave w owns rows 2w, 2w+1; 16 values/lane/row ----
    float rs[2];
    {
        unsigned u[2][16];
        float m[2];
#pragma unroll
        for (int rr = 0; rr < 2; ++rr) {
            const float* Srow = &S[(w * 2 + rr) << 10];
            float mloc = -1e30f;
#pragma unroll
            for (int i = 0; i < 4; ++i) {
                f32x4 v = *(const f32x4*)&Srow[(lane + (i << 6)) << 2];
#pragma unroll
                for (int k = 0; k < 4; ++k) {
                    float f = v[k];
                    mloc = fmaxf(mloc, f);
                    unsigned uu = __float_as_uint(f);
                    u[rr][i * 4 + k] = (uu & 0x80000000u) ? ~uu : (uu | 0x80000000u);
                }
            }
            m[rr] = mloc;
        }
        __syncthreads();   // all S fp32 reads done; Pb writes become safe

#pragma unroll
        for (int off = 32; off; off >>= 1)
#pragma unroll
            for (int rr = 0; rr < 2; ++rr)
                m[rr] = fmaxf(m[rr], __shfl_xor(m[rr], off));

        unsigned ans[2] = {0u, 0u};
        int done = 0;
#pragma unroll 1
        for (int bit = 31; bit >= 0; --bit) {
            if (done == 3) break;
#pragma unroll
            for (int rr = 0; rr < 2; ++rr) {
                unsigned cand = ans[rr] | (1u << bit);
                int cnt = 0;
#pragma unroll
                for (int i = 0; i < 16; ++i)
                    cnt += (int)__popcll(__ballot(u[rr][i] >= cand));
                if (!((done >> rr) & 1) && cnt >= TOPK) {
                    ans[rr] = cand;
                    if (cnt == TOPK) done |= (1 << rr);
                }
            }
        }

        // masked exp (base = row max), write P as bf16 into Pb
#pragma unroll
        for (int rr = 0; rr < 2; ++rr) {
            const int row = w * 2 + rr;
            float ssum = 0.f;
#pragma unroll
            for (int i = 0; i < 4; ++i) {
                us4 eh;
#pragma unroll
                for (int k = 0; k < 4; ++k) {
                    unsigned uu = u[rr][i * 4 + k];
                    unsigned fb = (uu & 0x80000000u) ? (uu & 0x7fffffffu) : ~uu;
                    float f = __uint_as_float(fb);
                    float ev = (uu >= ans[rr]) ? exp2f((f - m[rr]) * LOG2E) : 0.f;
                    ssum += ev;
                    eh[k] = f2bf(ev);
                }
                *(us4*)&Pb[row * 1032 + 4 * lane + 256 * i] = eh;
            }
            rs[rr] = ssum;
        }
#pragma unroll
        for (int off = 32; off; off >>= 1)
#pragma unroll
            for (int rr = 0; rr < 2; ++rr)
                rs[rr] += __shfl_xor(rs[rr], off);
    }
    __syncthreads();

    // ---- Phase 3: partial O over k in [w*128, w*128+128) ----
    f32x4 oacc[4];
#pragma unroll
    for (int nt = 0; nt < 4; ++nt) oacc[nt] = (f32x4){0.f, 0.f, 0.f, 0.f};

    for (int step = 0; step < 4; ++step) {
        int k0 = w * 128 + step * 32;
        bf16x8 a = *(const bf16x8*)&Pb[l16 * 1032 + k0 + quad * 8];
#pragma unroll
        for (int nt = 0; nt < 4; ++nt) {
            bf16x8 bfrag = *(const bf16x8*)(Vp + (size_t)(nt * 16 + l16) * 1024 + k0 + quad * 8);
            oacc[nt] = __builtin_amdgcn_mfma_f32_16x16x32_bf16(a, bfrag, oacc[nt], 0, 0, 0);
        }
    }
    __syncthreads();   // all Pb reads done; S region reusable for partials

    // partials: S[(w*16 + row)*68 + col] (stride 68 -> 2-way max); rsum at 8704
#pragma unroll
    for (int nt = 0; nt < 4; ++nt)
#pragma unroll
        for (int r = 0; r < 4; ++r)
            S[(w * 16 + quad * 4 + r) * 68 + nt * 16 + l16] = oacc[nt][r];
    if (lane == 0) {
        S[8704 + w * 2 + 0] = rs[0];
        S[8704 + w * 2 + 1] = rs[1];
    }
    __syncthreads();

    if (tid < 256) {
        int row = tid >> 4, ds = (tid & 15) * 4;
        f32x4 o = {0.f, 0.f, 0.f, 0.f};
#pragma unroll
        for (int ww = 0; ww < 8; ++ww)
            o += *(const f32x4*)&S[(ww * 16 + row) * 68 + ds];
        float inv = 1.f / S[8704 + row];
        int srow = qt * 16 + row;
        us4 res;
#pragma unroll
        for (int k = 0; k < 4; ++k) res[k] = f2bf(o[k] * inv);
        *(us4*)&Aob[((size_t)(bb * 1024 + srow)) * 768 + h * 64 + ds] = res;
    }
}

extern "C" void kernel_launch(void* const* d_in, const int* in_sizes, int n_in,
                              void* d_out, int out_size, void* d_ws, size_t ws_size,
                              hipStream_t stream)
{
    const float* X     = (const float*)d_in[0];
    const float* Wqkv  = (const float*)d_in[1];
    const float* bqkv  = (const float*)d_in[2];
    const float* Wproj = (const float*)d_in[3];
    const float* bproj = (const float*)d_in[4];
    float* out = (float*)d_out;

    unsigned short* us = (unsigned short*)d_ws;
    const size_t P = (size_t)8192 * 768;          // 6291456
    unsigned short* Xhi = us;
    unsigned short* Xlo = Xhi + P;
    unsigned short* Wqh = Xlo + P;                // [2304][768]
    unsigned short* Wql = Wqh + (size_t)2304 * 768;
    unsigned short* Wph = Wql + (size_t)2304 * 768;  // [768][768]
    unsigned short* Wpl = Wph + (size_t)768 * 768;
    unsigned short* Qhi = Wpl + (size_t)768 * 768;
    unsigned short* Qlo = Qhi + P;
    unsigned short* Khi = Qlo + P;
    unsigned short* Klo = Khi + P;
    unsigned short* Vt  = Klo + P;
    unsigned short* Aob = Xhi;   // reuse: X consumed by qkv before attn writes Aob

    cast_x_kernel<<<3072, 256, 0, stream>>>(X, Xhi, Xlo);
    transpose_split_kernel<<<dim3(72, 24), 256, 0, stream>>>(Wqkv, Wqh, Wql, 768, 2304);
    transpose_split_kernel<<<dim3(24, 24), 256, 0, stream>>>(Wproj, Wph, Wpl, 768, 768);
    qkv_mfma_kernel<<<dim3(18, 64), 256, 0, stream>>>(Xhi, Xlo, Wqh, Wql, bqkv,
                                                      Qhi, Qlo, Khi, Klo, Vt);
    attn_kernel<<<dim3(64, 96), 512, 0, stream>>>(Qhi, Qlo, Khi, Klo, Vt, Aob);
    proj_mfma_kernel<<<dim3(6, 64), 256, 0, stream>>>(Aob, Wph, bproj, out);
}

// Round 8
// 599.948 us; speedup vs baseline: 1.3090x; 1.0232x over previous
//
#include <hip/hip_runtime.h>

#define LOG2E 1.44269504088896340736f
#define TOPK 409

typedef __attribute__((ext_vector_type(8))) short bf16x8;
typedef __attribute__((ext_vector_type(4))) float f32x4;
typedef __attribute__((ext_vector_type(4))) unsigned short us4;

__device__ __forceinline__ unsigned short f2bf(float f) {
    unsigned u = __float_as_uint(f);
    unsigned r = (u + 0x7fffu + ((u >> 16) & 1u)) >> 16;   // RNE
    return (unsigned short)r;
}
__device__ __forceinline__ float bf2f(unsigned short h) {
    return __uint_as_float(((unsigned)h) << 16);
}

// ---------------------------------------------------------------------------
// Cast X fp32 -> Xhi/Xlo bf16 (grid covers 6291456 elements exactly)
// ---------------------------------------------------------------------------
__global__ __launch_bounds__(256) void cast_x_kernel(
    const float* __restrict__ X, unsigned short* __restrict__ Xhi,
    unsigned short* __restrict__ Xlo)
{
    int i = (blockIdx.x * 256 + threadIdx.x) * 8;
    float4 a = *(const float4*)&X[i];
    float4 b = *(const float4*)&X[i + 4];
    float v[8] = {a.x, a.y, a.z, a.w, b.x, b.y, b.z, b.w};
    us4 h0, h1, l0, l1;
#pragma unroll
    for (int k = 0; k < 4; ++k) {
        unsigned short hb = f2bf(v[k]);
        h0[k] = hb; l0[k] = f2bf(v[k] - bf2f(hb));
        unsigned short hb2 = f2bf(v[4 + k]);
        h1[k] = hb2; l1[k] = f2bf(v[4 + k] - bf2f(hb2));
    }
    *(us4*)&Xhi[i] = h0; *(us4*)&Xhi[i + 4] = h1;
    *(us4*)&Xlo[i] = l0; *(us4*)&Xlo[i + 4] = l1;
}

// ---------------------------------------------------------------------------
// W[K,N] fp32 -> Th/Tl[N,K] bf16 (transpose + hi/lo split), 32x32 LDS tiles
// ---------------------------------------------------------------------------
__global__ __launch_bounds__(256) void transpose_split_kernel(
    const float* __restrict__ W, unsigned short* __restrict__ Th,
    unsigned short* __restrict__ Tl, int K, int N)
{
    __shared__ float T[32][33];
    const int tx = threadIdx.x & 31, ty = threadIdx.x >> 5;   // ty 0..7
    const int n0 = blockIdx.x * 32, k0 = blockIdx.y * 32;
#pragma unroll
    for (int r = 0; r < 4; ++r)
        T[ty + r * 8][tx] = W[(size_t)(k0 + ty + r * 8) * N + n0 + tx];
    __syncthreads();
#pragma unroll
    for (int r = 0; r < 4; ++r) {
        int nl = ty + r * 8;
        float v = T[tx][nl];
        unsigned short hb = f2bf(v);
        Th[(size_t)(n0 + nl) * K + k0 + tx] = hb;
        Tl[(size_t)(n0 + nl) * K + k0 + tx] = f2bf(v - bf2f(hb));
    }
}

// ---------------------------------------------------------------------------
// QKV GEMM via MFMA (unchanged from R4/R6 — proven)
// ---------------------------------------------------------------------------
__global__ __launch_bounds__(256) void qkv_mfma_kernel(
    const unsigned short* __restrict__ Xhi, const unsigned short* __restrict__ Xlo,
    const unsigned short* __restrict__ Bhg, const unsigned short* __restrict__ Blg,
    const float* __restrict__ bias,
    unsigned short* __restrict__ Qhi, unsigned short* __restrict__ Qlo,
    unsigned short* __restrict__ Khi, unsigned short* __restrict__ Klo,
    unsigned short* __restrict__ Vt)
{
    __shared__ unsigned short Ah[128 * 32], Al[128 * 32];
    __shared__ unsigned short Bh[128 * 32], Bl[128 * 32];
    const int tid = threadIdx.x;
    const int n0 = blockIdx.x * 128, m0 = blockIdx.y * 128;
    const int which = n0 / 768;               // block-uniform
    const bool threep = (which < 2);
    const int lane = tid & 63, l16 = lane & 15, quad = lane >> 4;
    const int w = tid >> 6, wm = w >> 1, wn = w & 1;

    f32x4 acc[4][4];
#pragma unroll
    for (int mi = 0; mi < 4; ++mi)
#pragma unroll
        for (int ni = 0; ni < 4; ++ni) acc[mi][ni] = (f32x4){0.f, 0.f, 0.f, 0.f};

    const int r0 = tid >> 2, kc = (tid & 3) * 8;   // staging: rows r0, r0+64
    const int r1 = r0 + 64;

    for (int k0 = 0; k0 < 768; k0 += 32) {
        bf16x8 ah0 = *(const bf16x8*)&Xhi[(size_t)(m0 + r0) * 768 + k0 + kc];
        bf16x8 ah1 = *(const bf16x8*)&Xhi[(size_t)(m0 + r1) * 768 + k0 + kc];
        bf16x8 bh0 = *(const bf16x8*)&Bhg[(size_t)(n0 + r0) * 768 + k0 + kc];
        bf16x8 bh1 = *(const bf16x8*)&Bhg[(size_t)(n0 + r1) * 768 + k0 + kc];
        bf16x8 al0 = {}, al1 = {}, bl0 = {}, bl1 = {};
        if (threep) {
            al0 = *(const bf16x8*)&Xlo[(size_t)(m0 + r0) * 768 + k0 + kc];
            al1 = *(const bf16x8*)&Xlo[(size_t)(m0 + r1) * 768 + k0 + kc];
            bl0 = *(const bf16x8*)&Blg[(size_t)(n0 + r0) * 768 + k0 + kc];
            bl1 = *(const bf16x8*)&Blg[(size_t)(n0 + r1) * 768 + k0 + kc];
        }
        __syncthreads();
        *(bf16x8*)&Ah[r0 * 32 + kc] = ah0;
        *(bf16x8*)&Ah[r1 * 32 + kc] = ah1;
        *(bf16x8*)&Bh[r0 * 32 + kc] = bh0;
        *(bf16x8*)&Bh[r1 * 32 + kc] = bh1;
        if (threep) {
            *(bf16x8*)&Al[r0 * 32 + kc] = al0;
            *(bf16x8*)&Al[r1 * 32 + kc] = al1;
            *(bf16x8*)&Bl[r0 * 32 + kc] = bl0;
            *(bf16x8*)&Bl[r1 * 32 + kc] = bl1;
        }
        __syncthreads();

        bf16x8 fah[4], fal[4];
#pragma unroll
        for (int mi = 0; mi < 4; ++mi) {
            int off = (wm * 64 + mi * 16 + l16) * 32 + quad * 8;
            fah[mi] = *(const bf16x8*)&Ah[off];
            if (threep) fal[mi] = *(const bf16x8*)&Al[off];
        }
#pragma unroll
        for (int ni = 0; ni < 4; ++ni) {
            int off = (wn * 64 + ni * 16 + l16) * 32 + quad * 8;
            bf16x8 fbh = *(const bf16x8*)&Bh[off];
            if (threep) {
                bf16x8 fbl = *(const bf16x8*)&Bl[off];
#pragma unroll
                for (int mi = 0; mi < 4; ++mi) {
                    acc[mi][ni] = __builtin_amdgcn_mfma_f32_16x16x32_bf16(fah[mi], fbh, acc[mi][ni], 0, 0, 0);
                    acc[mi][ni] = __builtin_amdgcn_mfma_f32_16x16x32_bf16(fah[mi], fbl, acc[mi][ni], 0, 0, 0);
                    acc[mi][ni] = __builtin_amdgcn_mfma_f32_16x16x32_bf16(fal[mi], fbh, acc[mi][ni], 0, 0, 0);
                }
            } else {
#pragma unroll
                for (int mi = 0; mi < 4; ++mi)
                    acc[mi][ni] = __builtin_amdgcn_mfma_f32_16x16x32_bf16(fah[mi], fbh, acc[mi][ni], 0, 0, 0);
            }
        }
    }

#pragma unroll
    for (int mi = 0; mi < 4; ++mi) {
#pragma unroll
        for (int ni = 0; ni < 4; ++ni) {
            int nb = n0 + wn * 64 + ni * 16 + l16;
            int rem = nb - which * 768;
            int h = rem >> 6, d = rem & 63;
            float bv = bias[nb];
#pragma unroll
            for (int r = 0; r < 4; ++r) {
                int m = m0 + wm * 64 + mi * 16 + quad * 4 + r;
                int bb = m >> 10, s = m & 1023;
                int head = bb * 12 + h;
                float val = acc[mi][ni][r] + bv;
                if (which == 2) {
                    Vt[(size_t)head * 65536 + (size_t)d * 1024 + s] = f2bf(val);
                } else {
                    unsigned short hb = f2bf(val);
                    unsigned short lb = f2bf(val - bf2f(hb));
                    size_t idx = (size_t)head * 65536 + (size_t)s * 64 + d;
                    if (which == 0) { Qhi[idx] = hb; Qlo[idx] = lb; }
                    else            { Khi[idx] = hb; Klo[idx] = lb; }
                }
            }
        }
    }
}

// ---------------------------------------------------------------------------
// Proj GEMM via MFMA (unchanged from R4/R6 — proven)
// ---------------------------------------------------------------------------
__global__ __launch_bounds__(256) void proj_mfma_kernel(
    const unsigned short* __restrict__ Ag, const unsigned short* __restrict__ Bhg,
    const float* __restrict__ bias, float* __restrict__ OUT)
{
    __shared__ unsigned short Ah[128 * 32];
    __shared__ unsigned short Bh[128 * 32];
    const int tid = threadIdx.x;
    const int n0 = blockIdx.x * 128, m0 = blockIdx.y * 128;
    const int lane = tid & 63, l16 = lane & 15, quad = lane >> 4;
    const int w = tid >> 6, wm = w >> 1, wn = w & 1;

    f32x4 acc[4][4];
#pragma unroll
    for (int mi = 0; mi < 4; ++mi)
#pragma unroll
        for (int ni = 0; ni < 4; ++ni) acc[mi][ni] = (f32x4){0.f, 0.f, 0.f, 0.f};

    const int r0 = tid >> 2, kc = (tid & 3) * 8;
    const int r1 = r0 + 64;

    for (int k0 = 0; k0 < 768; k0 += 32) {
        bf16x8 ah0 = *(const bf16x8*)&Ag[(size_t)(m0 + r0) * 768 + k0 + kc];
        bf16x8 ah1 = *(const bf16x8*)&Ag[(size_t)(m0 + r1) * 768 + k0 + kc];
        bf16x8 bh0 = *(const bf16x8*)&Bhg[(size_t)(n0 + r0) * 768 + k0 + kc];
        bf16x8 bh1 = *(const bf16x8*)&Bhg[(size_t)(n0 + r1) * 768 + k0 + kc];
        __syncthreads();
        *(bf16x8*)&Ah[r0 * 32 + kc] = ah0;
        *(bf16x8*)&Ah[r1 * 32 + kc] = ah1;
        *(bf16x8*)&Bh[r0 * 32 + kc] = bh0;
        *(bf16x8*)&Bh[r1 * 32 + kc] = bh1;
        __syncthreads();

        bf16x8 fah[4];
#pragma unroll
        for (int mi = 0; mi < 4; ++mi)
            fah[mi] = *(const bf16x8*)&Ah[(wm * 64 + mi * 16 + l16) * 32 + quad * 8];
#pragma unroll
        for (int ni = 0; ni < 4; ++ni) {
            bf16x8 fbh = *(const bf16x8*)&Bh[(wn * 64 + ni * 16 + l16) * 32 + quad * 8];
#pragma unroll
            for (int mi = 0; mi < 4; ++mi)
                acc[mi][ni] = __builtin_amdgcn_mfma_f32_16x16x32_bf16(fah[mi], fbh, acc[mi][ni], 0, 0, 0);
        }
    }

#pragma unroll
    for (int mi = 0; mi < 4; ++mi)
#pragma unroll
        for (int ni = 0; ni < 4; ++ni) {
            int nb = n0 + wn * 64 + ni * 16 + l16;
            float bv = bias[nb];
#pragma unroll
            for (int r = 0; r < 4; ++r) {
                int m = m0 + wm * 64 + mi * 16 + quad * 4 + r;
                OUT[(size_t)m * 768 + nb] = acc[mi][ni][r] + bv;
            }
        }
}

// ---------------------------------------------------------------------------
// Attention, 1024 threads (16 waves), 16 q-rows/block, 64 KB LDS
// -> 2 blocks/CU x 16 waves = 8 waves/SIMD (full occupancy).
//  Phase 1: wave w computes score cols [w*64,(w+1)*64) via MFMA -> S fp32.
//  Phase 2: wave w owns row w (16 vals/lane): exact binary search
//           (ballot+popcount, early exit), masked exp -> P bf16 into Pb
//           (aliases S after barrier). Serial chain hidden by 8-way TLP.
//  Phase 3: O-partial over k-strip [w*64,(w+1)*64) via bf16 MFMA; two-stage
//           cross-wave reduce (16->8 via LDS+register add, then 8-way sum).
// ---------------------------------------------------------------------------
__global__ __launch_bounds__(1024, 8) void attn_kernel(
    const unsigned short* __restrict__ Qhi, const unsigned short* __restrict__ Qlo,
    const unsigned short* __restrict__ Khi, const unsigned short* __restrict__ Klo,
    const unsigned short* __restrict__ Vt, unsigned short* __restrict__ Aob)
{
    __shared__ float S[16 * 1024];   // 64 KB. Aliased: Pb bf16 (33 KB), partials
    unsigned short* Pb = (unsigned short*)S;   // [16][1032] shorts

    const int head = blockIdx.y;
    const int qt = blockIdx.x;       // 16-row q tile
    const int bb = head / 12, h = head - bb * 12;
    const int tid = threadIdx.x;
    const int w = tid >> 6, lane = tid & 63;
    const int l16 = lane & 15, quad = lane >> 4;

    const size_t hbase = (size_t)head * 65536;
    const unsigned short* Qhp = Qhi + hbase + (size_t)(qt * 16) * 64;
    const unsigned short* Qlp = Qlo + hbase + (size_t)(qt * 16) * 64;
    const unsigned short* Khp = Khi + hbase;
    const unsigned short* Klp = Klo + hbase;
    const unsigned short* Vp  = Vt + hbase;   // [64][1024]

    bf16x8 qh0, qh1, ql0, ql1;
    {
        int off = l16 * 64 + quad * 8;
        qh0 = *(const bf16x8*)(Qhp + off);
        qh1 = *(const bf16x8*)(Qhp + off + 32);
        ql0 = *(const bf16x8*)(Qlp + off);
        ql1 = *(const bf16x8*)(Qlp + off + 32);
    }

    // ---- Phase 1: scores for cols [w*64, w*64+64) ----
    for (int t = 0; t < 4; ++t) {
        int col0 = w * 64 + t * 16;
        int off = (col0 + l16) * 64 + quad * 8;
        bf16x8 kh0 = *(const bf16x8*)(Khp + off);
        bf16x8 kh1 = *(const bf16x8*)(Khp + off + 32);
        bf16x8 kl0 = *(const bf16x8*)(Klp + off);
        bf16x8 kl1 = *(const bf16x8*)(Klp + off + 32);
        f32x4 acc = {0.f, 0.f, 0.f, 0.f};
        acc = __builtin_amdgcn_mfma_f32_16x16x32_bf16(qh0, kh0, acc, 0, 0, 0);
        acc = __builtin_amdgcn_mfma_f32_16x16x32_bf16(qh1, kh1, acc, 0, 0, 0);
        acc = __builtin_amdgcn_mfma_f32_16x16x32_bf16(qh0, kl0, acc, 0, 0, 0);
        acc = __builtin_amdgcn_mfma_f32_16x16x32_bf16(qh1, kl1, acc, 0, 0, 0);
        acc = __builtin_amdgcn_mfma_f32_16x16x32_bf16(ql0, kh0, acc, 0, 0, 0);
        acc = __builtin_amdgcn_mfma_f32_16x16x32_bf16(ql1, kh1, acc, 0, 0, 0);
#pragma unroll
        for (int r = 0; r < 4; ++r)
            S[(quad * 4 + r) * 1024 + col0 + l16] = acc[r] * 0.125f;
    }
    __syncthreads();

    // ---- Phase 2: wave w owns row w; 16 values/lane ----
    float rs;
    {
        const float* Srow = &S[w << 10];
        unsigned u[16];
        float m = -1e30f;
#pragma unroll
        for (int i = 0; i < 4; ++i) {
            f32x4 v = *(const f32x4*)&Srow[(lane + (i << 6)) << 2];
#pragma unroll
            for (int k = 0; k < 4; ++k) {
                float f = v[k];
                m = fmaxf(m, f);
                unsigned uu = __float_as_uint(f);
                u[i * 4 + k] = (uu & 0x80000000u) ? ~uu : (uu | 0x80000000u);
            }
        }
        __syncthreads();   // all S fp32 reads done; Pb writes become safe

#pragma unroll
        for (int off = 32; off; off >>= 1) m = fmaxf(m, __shfl_xor(m, off));

        unsigned ans = 0u;
        int done = 0;
#pragma unroll 1
        for (int bit = 31; bit >= 0; --bit) {
            if (done) break;
            unsigned cand = ans | (1u << bit);
            int cnt = 0;
#pragma unroll
            for (int i = 0; i < 16; ++i)
                cnt += (int)__popcll(__ballot(u[i] >= cand));
            if (cnt >= TOPK) {
                ans = cand;
                if (cnt == TOPK) done = 1;
            }
        }

        // masked exp (base = row max), write P as bf16 into Pb
        float ssum = 0.f;
#pragma unroll
        for (int i = 0; i < 4; ++i) {
            us4 eh;
#pragma unroll
            for (int k = 0; k < 4; ++k) {
                unsigned uu = u[i * 4 + k];
                unsigned fb = (uu & 0x80000000u) ? (uu & 0x7fffffffu) : ~uu;
                float f = __uint_as_float(fb);
                float ev = (uu >= ans) ? exp2f((f - m) * LOG2E) : 0.f;
                ssum += ev;
                eh[k] = f2bf(ev);
            }
            *(us4*)&Pb[w * 1032 + 4 * lane + 256 * i] = eh;
        }
#pragma unroll
        for (int off = 32; off; off >>= 1) ssum += __shfl_xor(ssum, off);
        rs = ssum;
    }
    __syncthreads();

    // ---- Phase 3: partial O over k in [w*64, w*64+64) ----
    f32x4 oacc[4];
#pragma unroll
    for (int nt = 0; nt < 4; ++nt) oacc[nt] = (f32x4){0.f, 0.f, 0.f, 0.f};

    for (int step = 0; step < 2; ++step) {
        int k0 = w * 64 + step * 32;
        bf16x8 a = *(const bf16x8*)&Pb[l16 * 1032 + k0 + quad * 8];
#pragma unroll
        for (int nt = 0; nt < 4; ++nt) {
            bf16x8 bfrag = *(const bf16x8*)(Vp + (size_t)(nt * 16 + l16) * 1024 + k0 + quad * 8);
            oacc[nt] = __builtin_amdgcn_mfma_f32_16x16x32_bf16(a, bfrag, oacc[nt], 0, 0, 0);
        }
    }
    __syncthreads();   // all Pb reads done; S region reusable

    // Stage A: waves 8..15 spill partials (rows 0..127, stride 68); rsum
    if (w >= 8) {
#pragma unroll
        for (int nt = 0; nt < 4; ++nt)
#pragma unroll
            for (int r = 0; r < 4; ++r)
                S[((w - 8) * 16 + quad * 4 + r) * 68 + nt * 16 + l16] = oacc[nt][r];
    }
    if (lane == 0) S[8704 + w] = rs;
    __syncthreads();

    // Stage B: waves 0..7 add the matching partial and write combined back
    if (w < 8) {
#pragma unroll
        for (int nt = 0; nt < 4; ++nt)
#pragma unroll
            for (int r = 0; r < 4; ++r) {
                int idx = (w * 16 + quad * 4 + r) * 68 + nt * 16 + l16;
                S[idx] = oacc[nt][r] + S[idx];
            }
    }
    __syncthreads();

    if (tid < 256) {
        int row = tid >> 4, ds = (tid & 15) * 4;
        f32x4 o = {0.f, 0.f, 0.f, 0.f};
#pragma unroll
        for (int ww = 0; ww < 8; ++ww)
            o += *(const f32x4*)&S[(ww * 16 + row) * 68 + ds];
        float inv = 1.f / S[8704 + row];
        int srow = qt * 16 + row;
        us4 res;
#pragma unroll
        for (int k = 0; k < 4; ++k) res[k] = f2bf(o[k] * inv);
        *(us4*)&Aob[((size_t)(bb * 1024 + srow)) * 768 + h * 64 + ds] = res;
    }
}

extern "C" void kernel_launch(void* const* d_in, const int* in_sizes, int n_in,
                              void* d_out, int out_size, void* d_ws, size_t ws_size,
                              hipStream_t stream)
{
    const float* X     = (const float*)d_in[0];
    const float* Wqkv  = (const float*)d_in[1];
    const float* bqkv  = (const float*)d_in[2];
    const float* Wproj = (const float*)d_in[3];
    const float* bproj = (const float*)d_in[4];
    float* out = (float*)d_out;

    unsigned short* us = (unsigned short*)d_ws;
    const size_t P = (size_t)8192 * 768;          // 6291456
    unsigned short* Xhi = us;
    unsigned short* Xlo = Xhi + P;
    unsigned short* Wqh = Xlo + P;                // [2304][768]
    unsigned short* Wql = Wqh + (size_t)2304 * 768;
    unsigned short* Wph = Wql + (size_t)2304 * 768;  // [768][768]
    unsigned short* Wpl = Wph + (size_t)768 * 768;
    unsigned short* Qhi = Wpl + (size_t)768 * 768;
    unsigned short* Qlo = Qhi + P;
    unsigned short* Khi = Qlo + P;
    unsigned short* Klo = Khi + P;
    unsigned short* Vt  = Klo + P;
    unsigned short* Aob = Xhi;   // reuse: X consumed by qkv before attn writes Aob

    cast_x_kernel<<<3072, 256, 0, stream>>>(X, Xhi, Xlo);
    transpose_split_kernel<<<dim3(72, 24), 256, 0, stream>>>(Wqkv, Wqh, Wql, 768, 2304);
    transpose_split_kernel<<<dim3(24, 24), 256, 0, stream>>>(Wproj, Wph, Wpl, 768, 768);
    qkv_mfma_kernel<<<dim3(18, 64), 256, 0, stream>>>(Xhi, Xlo, Wqh, Wql, bqkv,
                                                      Qhi, Qlo, Khi, Klo, Vt);
    attn_kernel<<<dim3(64, 96), 1024, 0, stream>>>(Qhi, Qlo, Khi, Klo, Vt, Aob);
    proj_mfma_kernel<<<dim3(6, 64), 256, 0, stream>>>(Aob, Wph, bproj, out);
}